// Round 18
// baseline (694.796 us; speedup 1.0000x reference)
//
#include <hip/hip_runtime.h>
#include <math.h>

#define NB 64
#define TPB 64   // ONE WAVE PER MATRIX; no LDS, no barriers, all-register

// 1/k! for k = 0..13 (degree-13 Taylor)
__device__ __constant__ float CF[16] = {
    1.0f,
    1.0f,
    0.5f,
    1.6666666666666666e-01f,
    4.1666666666666664e-02f,
    8.3333333333333332e-03f,
    1.3888888888888889e-03f,
    1.9841269841269841e-04f,
    2.4801587301587302e-05f,
    2.7557319223985893e-06f,
    2.7557319223985888e-07f,
    2.5052108385441720e-08f,
    2.0876756987868100e-09f,
    1.6059043836821613e-10f,
    1.1470745597729725e-11f,
    7.6471637318198164e-13f
};

typedef __attribute__((ext_vector_type(8))) short bf16x8;
typedef __attribute__((ext_vector_type(16))) float f32x16;
typedef __attribute__((ext_vector_type(4))) unsigned int u32x4;

#define MFMA32 __builtin_amdgcn_mfma_f32_32x32x16_bf16
#define BCH(x) __builtin_bit_cast(bf16x8, x)

// packed split: (x0,x1) -> hi word (bf16(x0)|bf16(x1)<<16), lo word (residuals)
__device__ __forceinline__ void split_pk(float x0, float x1, unsigned& ph, unsigned& pl) {
    unsigned h;
    asm("v_cvt_pk_bf16_f32 %0, %1, %2" : "=v"(h) : "v"(x0), "v"(x1));
    float h0 = __builtin_bit_cast(float, h << 16);
    float h1 = __builtin_bit_cast(float, h & 0xFFFF0000u);
    float r0 = x0 - h0;
    float r1 = x1 - h1;
    unsigned l;
    asm("v_cvt_pk_bf16_f32 %0, %1, %2" : "=v"(l) : "v"(r0), "v"(r1));
    ph = h; pl = l;
}

// exchange halves: after call, a = [a.lo32 | b.lo32], b = [a.hi32 | b.hi32]
__device__ __forceinline__ void pswap(unsigned& a, unsigned& b, int lh) {
#if __has_builtin(__builtin_amdgcn_permlane32_swap)
    auto r = __builtin_amdgcn_permlane32_swap((int)a, (int)b, false, false);
    a = (unsigned)r[0];
    b = (unsigned)r[1];
#else
    unsigned pa = (unsigned)__shfl_xor((int)a, 32);
    unsigned pb = (unsigned)__shfl_xor((int)b, 32);
    unsigned o0 = lh ? pb : a;
    unsigned o1 = lh ? b : pa;
    a = o0; b = o1;
#endif
}

// acc-layout tile values v[16] (= C[rb+4lh+8g+q][cb+l31]) -> 2 operand frags
// (hi+lo) for operand rowblock cb, k-range [rb, rb+32), via symmetry of C.
__device__ __forceinline__ void tile_to_op(const float* v, int lh, u32x4* fh, u32x4* fl) {
    unsigned Wh[4][2], Wl[4][2];
#pragma unroll
    for (int g = 0; g < 4; ++g) {
        split_pk(v[g * 4 + 0], v[g * 4 + 1], Wh[g][0], Wl[g][0]);
        split_pk(v[g * 4 + 2], v[g * 4 + 3], Wh[g][1], Wl[g][1]);
    }
#pragma unroll
    for (int p = 0; p < 2; ++p) {
        unsigned a0 = Wh[2 * p][0], b0 = Wh[2 * p + 1][0];
        unsigned a1 = Wh[2 * p][1], b1 = Wh[2 * p + 1][1];
        pswap(a0, b0, lh);
        pswap(a1, b1, lh);
        fh[p] = (u32x4){a0, a1, b0, b1};
        a0 = Wl[2 * p][0]; b0 = Wl[2 * p + 1][0];
        a1 = Wl[2 * p][1]; b1 = Wl[2 * p + 1][1];
        pswap(a0, b0, lh);
        pswap(a1, b1, lh);
        fl[p] = (u32x4){a0, a1, b0, b1};
    }
}

// acc = Ahi*Bhi + Alo*Bhi + Ahi*Blo over K=64
__device__ __forceinline__ f32x16 mm3v(const u32x4* ah, const u32x4* al,
                                       const u32x4* bh, const u32x4* bl) {
    f32x16 acc = {};
#pragma unroll
    for (int f = 0; f < 4; ++f) acc = MFMA32(BCH(ah[f]), BCH(bh[f]), acc, 0, 0, 0);
#pragma unroll
    for (int f = 0; f < 4; ++f) acc = MFMA32(BCH(al[f]), BCH(bh[f]), acc, 0, 0, 0);
#pragma unroll
    for (int f = 0; f < 4; ++f) acc = MFMA32(BCH(ah[f]), BCH(bl[f]), acc, 0, 0, 0);
    return acc;
}

// write acc tile (R,C) to global via symmetry: row C*32+l31, cols R*32+4lh+8g+q
__device__ __forceinline__ void wr_tile(float* __restrict__ out, size_t base,
                                        int C, int R, int l31, int lh, const float* w) {
    float* rowp = out + base + (size_t)(C * 32 + l31) * NB + R * 32 + 4 * lh;
#pragma unroll
    for (int g = 0; g < 4; ++g) {
        float4 v = make_float4(w[g * 4 + 0], w[g * 4 + 1], w[g * 4 + 2], w[g * 4 + 3]);
        *reinterpret_cast<float4*>(rowp + 8 * g) = v;
    }
}

// x tile values at acc positions for tile (R,C): row ptr rp (= row C*32+l31), cols R*32+4lh+8g+q
__device__ __forceinline__ void load_x(const float* rp, int colbase, float* xr) {
#pragma unroll
    for (int g = 0; g < 4; ++g) {
        float4 t = *reinterpret_cast<const float4*>(rp + colbase + 8 * g);
        xr[g * 4 + 0] = t.x; xr[g * 4 + 1] = t.y;
        xr[g * 4 + 2] = t.z; xr[g * 4 + 3] = t.w;
    }
}

// (64,3): target 3 waves/EU (<=170 regs). Steady live state with x reloaded
// from global is ~150 regs (Y32+P32+acc32+xr32+misc), unlike R15's x-resident
// variant (~230, spilled at 84-reg force). Spill signature = WRITE >> 300 MB.
__global__ __launch_bounds__(TPB, 3)
void spd_expmap_reg(const float* __restrict__ in, float* __restrict__ out)
{
    const int lane = threadIdx.x & 63;
    const int l31 = lane & 31;
    const int lh  = lane >> 5;
    const size_t base = (size_t)blockIdx.x * (NB * NB);
    const float* rp0 = in + base + (size_t)l31 * NB;        // row l31
    const float* rp1 = rp0 + (size_t)32 * NB;               // row 32+l31

    unsigned dmask = 0;
#pragma unroll
    for (int g = 0; g < 4; ++g)
#pragma unroll
        for (int q = 0; q < 4; ++q)
            if (4 * lh + 8 * g + q == l31) dmask |= 1u << (g * 4 + q);

    // ---- X operand frags straight from global ----
    u32x4 XH[2][4], XL[2][4];
#pragma unroll
    for (int R = 0; R < 2; ++R) {
        const float* rp = R ? rp1 : rp0;
#pragma unroll
        for (int f = 0; f < 4; ++f) {
            const float* q = rp + 16 * f + 8 * lh;
            float4 a = *reinterpret_cast<const float4*>(q);
            float4 b = *reinterpret_cast<const float4*>(q + 4);
            unsigned h0, l0, h1, l1, h2, l2, h3, l3;
            split_pk(a.x, a.y, h0, l0);
            split_pk(a.z, a.w, h1, l1);
            split_pk(b.x, b.y, h2, l2);
            split_pk(b.z, b.w, h3, l3);
            XH[R][f] = (u32x4){h0, h1, h2, h3};
            XL[R][f] = (u32x4){l0, l1, l2, l3};
        }
    }

    // ---- mm1: acc tiles of A*A + Frobenius ----
    f32x16 a00 = mm3v(XH[0], XL[0], XH[0], XL[0]);
    f32x16 a01 = mm3v(XH[0], XL[0], XH[1], XL[1]);
    f32x16 a10 = mm3v(XH[1], XL[1], XH[0], XL[0]);
    f32x16 a11 = mm3v(XH[1], XL[1], XH[1], XL[1]);

    float fr = 0.f;
#pragma unroll
    for (int r = 0; r < 16; ++r)
        fr += a00[r]*a00[r] + a01[r]*a01[r] + a10[r]*a10[r] + a11[r]*a11[r];
#pragma unroll
    for (int off = 32; off; off >>= 1) fr += __shfl_xor(fr, off);

    // ||A||_2 <= (sum (A^2)_ij^2)^(1/4); tolerate ||X|| <= 4
    const float bound = sqrtf(sqrtf(fr));
    int sexp = 0;
    if (bound > 4.f) {
        sexp = (int)ceilf(log2f(bound)) - 2;
        if (sexp < 0) sexp = 0;
        if (sexp > 24) sexp = 24;
    }
    const float sc1 = exp2f(-(float)sexp);
    const float sc2 = sc1 * sc1;

    // ---- Yop = operand form of (A*A)*4^-s (X frags die here) ----
    u32x4 YH[2][4], YL[2][4];
    {
        float v[16];
#pragma unroll
        for (int r = 0; r < 16; ++r) v[r] = a00[r] * sc2;
        tile_to_op(v, lh, &YH[0][0], &YL[0][0]);
#pragma unroll
        for (int r = 0; r < 16; ++r) v[r] = a10[r] * sc2;
        tile_to_op(v, lh, &YH[0][2], &YL[0][2]);
#pragma unroll
        for (int r = 0; r < 16; ++r) v[r] = a01[r] * sc2;
        tile_to_op(v, lh, &YH[1][0], &YL[1][0]);
#pragma unroll
        for (int r = 0; r < 16; ++r) v[r] = a11[r] * sc2;
        tile_to_op(v, lh, &YH[1][2], &YL[1][2]);
    }

    // ---- Pop init = operand form of CF[12]*I + CF[13]*X (x from global, scale folded) ----
    u32x4 PH[2][4], PL[2][4];
    {
        const float c13s = CF[13] * sc1;
        float xr[16], w[16];
        load_x(rp0, 4 * lh, xr);                          // tile (0,0), diag
#pragma unroll
        for (int r = 0; r < 16; ++r)
            w[r] = fmaf(c13s, xr[r], (((dmask >> r) & 1) ? CF[12] : 0.f));
        tile_to_op(w, lh, &PH[0][0], &PL[0][0]);
        load_x(rp0, 32 + 4 * lh, xr);                     // tile (1,0)
#pragma unroll
        for (int r = 0; r < 16; ++r) w[r] = c13s * xr[r];
        tile_to_op(w, lh, &PH[0][2], &PL[0][2]);
        load_x(rp1, 4 * lh, xr);                          // tile (0,1)
#pragma unroll
        for (int r = 0; r < 16; ++r) w[r] = c13s * xr[r];
        tile_to_op(w, lh, &PH[1][0], &PL[1][0]);
        load_x(rp1, 32 + 4 * lh, xr);                     // tile (1,1), diag
#pragma unroll
        for (int r = 0; r < 16; ++r)
            w[r] = fmaf(c13s, xr[r], (((dmask >> r) & 1) ? CF[12] : 0.f));
        tile_to_op(w, lh, &PH[1][2], &PL[1][2]);
    }

    // ---- Horner (deg-13): P <- (cI*I + cX*X) + Y*P ; phased, x reloaded per phase ----
#pragma unroll 1
    for (int j = 5; j >= 0; --j) {
        const float cI = CF[2 * j], cXs = CF[2 * j + 1] * sc1;
        const bool last = (j == 0) && (sexp == 0);
        {   // phase A: B-operand = P col-block 0 -> tiles (0,0) diag, (1,0)
            float xa[16], xb[16];
            load_x(rp0, 4 * lh, xa);                      // issued before chain
            load_x(rp0, 32 + 4 * lh, xb);
            f32x16 t0 = mm3v(YH[0], YL[0], PH[0], PL[0]);
            f32x16 t1 = mm3v(YH[1], YL[1], PH[0], PL[0]);
            float w[16];
#pragma unroll
            for (int r = 0; r < 16; ++r)
                w[r] = t0[r] + fmaf(cXs, xa[r], (((dmask >> r) & 1) ? cI : 0.f));
            if (last) wr_tile(out, base, 0, 0, l31, lh, w);
            else      tile_to_op(w, lh, &PH[0][0], &PL[0][0]);
#pragma unroll
            for (int r = 0; r < 16; ++r) w[r] = fmaf(cXs, xb[r], t1[r]);
            if (last) wr_tile(out, base, 0, 1, l31, lh, w);
            else      tile_to_op(w, lh, &PH[0][2], &PL[0][2]);
        }
        {   // phase B: B-operand = OLD P col-block 1 -> tiles (0,1), (1,1) diag
            float xa[16], xb[16];
            load_x(rp1, 4 * lh, xa);
            load_x(rp1, 32 + 4 * lh, xb);
            f32x16 t0 = mm3v(YH[0], YL[0], PH[1], PL[1]);
            f32x16 t1 = mm3v(YH[1], YL[1], PH[1], PL[1]);
            float w[16];
#pragma unroll
            for (int r = 0; r < 16; ++r) w[r] = fmaf(cXs, xa[r], t0[r]);
            if (last) wr_tile(out, base, 1, 0, l31, lh, w);
            else      tile_to_op(w, lh, &PH[1][0], &PL[1][0]);
#pragma unroll
            for (int r = 0; r < 16; ++r)
                w[r] = t1[r] + fmaf(cXs, xb[r], (((dmask >> r) & 1) ? cI : 0.f));
            if (last) wr_tile(out, base, 1, 1, l31, lh, w);
            else      tile_to_op(w, lh, &PH[1][2], &PL[1][2]);
        }
    }

    // ---- squarings: P <- P*P ; final streams to global ----
#pragma unroll 1
    for (int t = 0; t < sexp; ++t) {
        f32x16 s00 = mm3v(PH[0], PL[0], PH[0], PL[0]);
        f32x16 s01 = mm3v(PH[0], PL[0], PH[1], PL[1]);
        f32x16 s10 = mm3v(PH[1], PL[1], PH[0], PL[0]);
        f32x16 s11 = mm3v(PH[1], PL[1], PH[1], PL[1]);
        if (t == sexp - 1) {
            wr_tile(out, base, 0, 0, l31, lh, (const float*)&s00);
            wr_tile(out, base, 0, 1, l31, lh, (const float*)&s10);
            wr_tile(out, base, 1, 0, l31, lh, (const float*)&s01);
            wr_tile(out, base, 1, 1, l31, lh, (const float*)&s11);
        } else {
            tile_to_op((const float*)&s00, lh, &PH[0][0], &PL[0][0]);
            tile_to_op((const float*)&s10, lh, &PH[0][2], &PL[0][2]);
            tile_to_op((const float*)&s01, lh, &PH[1][0], &PL[1][0]);
            tile_to_op((const float*)&s11, lh, &PH[1][2], &PL[1][2]);
        }
    }
}

extern "C" void kernel_launch(void* const* d_in, const int* in_sizes, int n_in,
                              void* d_out, int out_size, void* d_ws, size_t ws_size,
                              hipStream_t stream) {
    const float* in = reinterpret_cast<const float*>(d_in[0]);
    float* out = reinterpret_cast<float*>(d_out);
    const int nmat = in_sizes[0] / (NB * NB);
    hipLaunchKernelGGL(spd_expmap_reg, dim3(nmat), dim3(TPB), 0, stream, in, out);
}

// Round 19
// 265.735 us; speedup vs baseline: 2.6146x; 2.6146x over previous
//
#include <hip/hip_runtime.h>
#include <math.h>

#define NB 64
#define TPB 64   // ONE WAVE PER MATRIX; no LDS, no barriers, all-register

// 1/k! for k = 0..13 (degree-13 Taylor)
__device__ __constant__ float CF[16] = {
    1.0f,
    1.0f,
    0.5f,
    1.6666666666666666e-01f,
    4.1666666666666664e-02f,
    8.3333333333333332e-03f,
    1.3888888888888889e-03f,
    1.9841269841269841e-04f,
    2.4801587301587302e-05f,
    2.7557319223985893e-06f,
    2.7557319223985888e-07f,
    2.5052108385441720e-08f,
    2.0876756987868100e-09f,
    1.6059043836821613e-10f,
    1.1470745597729725e-11f,
    7.6471637318198164e-13f
};

typedef __attribute__((ext_vector_type(8))) short bf16x8;
typedef __attribute__((ext_vector_type(16))) float f32x16;
typedef __attribute__((ext_vector_type(4))) unsigned int u32x4;

#define MFMA32 __builtin_amdgcn_mfma_f32_32x32x16_bf16
#define BCH(x) __builtin_bit_cast(bf16x8, x)

// packed split: (x0,x1) -> hi word (bf16(x0)|bf16(x1)<<16), lo word (residuals)
__device__ __forceinline__ void split_pk(float x0, float x1, unsigned& ph, unsigned& pl) {
    unsigned h;
    asm("v_cvt_pk_bf16_f32 %0, %1, %2" : "=v"(h) : "v"(x0), "v"(x1));
    float h0 = __builtin_bit_cast(float, h << 16);
    float h1 = __builtin_bit_cast(float, h & 0xFFFF0000u);
    float r0 = x0 - h0;
    float r1 = x1 - h1;
    unsigned l;
    asm("v_cvt_pk_bf16_f32 %0, %1, %2" : "=v"(l) : "v"(r0), "v"(r1));
    ph = h; pl = l;
}

// exchange halves: after call, a = [a.lo32 | b.lo32], b = [a.hi32 | b.hi32]
__device__ __forceinline__ void pswap(unsigned& a, unsigned& b, int lh) {
#if __has_builtin(__builtin_amdgcn_permlane32_swap)
    auto r = __builtin_amdgcn_permlane32_swap((int)a, (int)b, false, false);
    a = (unsigned)r[0];
    b = (unsigned)r[1];
#else
    unsigned pa = (unsigned)__shfl_xor((int)a, 32);
    unsigned pb = (unsigned)__shfl_xor((int)b, 32);
    unsigned o0 = lh ? pb : a;
    unsigned o1 = lh ? b : pa;
    a = o0; b = o1;
#endif
}

// acc-layout tile values v[16] (= C[rb+4lh+8g+q][cb+l31]) -> 2 operand frags
// (hi+lo) for operand rowblock cb, k-range [rb, rb+32), via symmetry of C.
__device__ __forceinline__ void tile_to_op(const float* v, int lh, u32x4* fh, u32x4* fl) {
    unsigned Wh[4][2], Wl[4][2];
#pragma unroll
    for (int g = 0; g < 4; ++g) {
        split_pk(v[g * 4 + 0], v[g * 4 + 1], Wh[g][0], Wl[g][0]);
        split_pk(v[g * 4 + 2], v[g * 4 + 3], Wh[g][1], Wl[g][1]);
    }
#pragma unroll
    for (int p = 0; p < 2; ++p) {
        unsigned a0 = Wh[2 * p][0], b0 = Wh[2 * p + 1][0];
        unsigned a1 = Wh[2 * p][1], b1 = Wh[2 * p + 1][1];
        pswap(a0, b0, lh);
        pswap(a1, b1, lh);
        fh[p] = (u32x4){a0, a1, b0, b1};
        a0 = Wl[2 * p][0]; b0 = Wl[2 * p + 1][0];
        a1 = Wl[2 * p][1]; b1 = Wl[2 * p + 1][1];
        pswap(a0, b0, lh);
        pswap(a1, b1, lh);
        fl[p] = (u32x4){a0, a1, b0, b1};
    }
}

// acc = C_in + Ahi*Bhi + Alo*Bhi + Ahi*Blo over K=64 (C-in carried through chain)
__device__ __forceinline__ f32x16 mm3v_ci(const u32x4* ah, const u32x4* al,
                                          const u32x4* bh, const u32x4* bl,
                                          f32x16 acc) {
#pragma unroll
    for (int f = 0; f < 4; ++f) acc = MFMA32(BCH(ah[f]), BCH(bh[f]), acc, 0, 0, 0);
#pragma unroll
    for (int f = 0; f < 4; ++f) acc = MFMA32(BCH(al[f]), BCH(bh[f]), acc, 0, 0, 0);
#pragma unroll
    for (int f = 0; f < 4; ++f) acc = MFMA32(BCH(ah[f]), BCH(bl[f]), acc, 0, 0, 0);
    return acc;
}

__device__ __forceinline__ f32x16 mm3v(const u32x4* ah, const u32x4* al,
                                       const u32x4* bh, const u32x4* bl) {
    f32x16 acc = {};
    return mm3v_ci(ah, al, bh, bl, acc);
}

// write acc tile (R,C) to global via symmetry: row C*32+l31, cols R*32+4lh+8g+q
__device__ __forceinline__ void wr_tile(float* __restrict__ out, size_t base,
                                        int C, int R, int l31, int lh, const float* w) {
    float* rowp = out + base + (size_t)(C * 32 + l31) * NB + R * 32 + 4 * lh;
#pragma unroll
    for (int g = 0; g < 4; ++g) {
        float4 v = make_float4(w[g * 4 + 0], w[g * 4 + 1], w[g * 4 + 2], w[g * 4 + 3]);
        *reinterpret_cast<float4*>(rowp + 8 * g) = v;
    }
}

// (64,2): 2 waves/EU -> 256-reg unified budget. R15/R16/R18 lesson: the live
// state (Y-op 64 + P-op 64 + accs + x) is ~250 regs; forcing 3 waves/EU spills
// catastrophically. This structure is the measured plateau (~265 us).
__global__ __launch_bounds__(TPB, 2)
void spd_expmap_reg(const float* __restrict__ in, float* __restrict__ out)
{
    const int lane = threadIdx.x & 63;
    const int l31 = lane & 31;
    const int lh  = lane >> 5;
    const size_t base = (size_t)blockIdx.x * (NB * NB);
    const float* rp0 = in + base + (size_t)l31 * NB;        // row l31
    const float* rp1 = rp0 + (size_t)32 * NB;               // row 32+l31

    unsigned dmask = 0;
#pragma unroll
    for (int g = 0; g < 4; ++g)
#pragma unroll
        for (int q = 0; q < 4; ++q)
            if (4 * lh + 8 * g + q == l31) dmask |= 1u << (g * 4 + q);

    // ---- X operand frags straight from global ----
    u32x4 XH[2][4], XL[2][4];
#pragma unroll
    for (int R = 0; R < 2; ++R) {
        const float* rp = R ? rp1 : rp0;
#pragma unroll
        for (int f = 0; f < 4; ++f) {
            const float* q = rp + 16 * f + 8 * lh;
            float4 a = *reinterpret_cast<const float4*>(q);
            float4 b = *reinterpret_cast<const float4*>(q + 4);
            unsigned h0, l0, h1, l1, h2, l2, h3, l3;
            split_pk(a.x, a.y, h0, l0);
            split_pk(a.z, a.w, h1, l1);
            split_pk(b.x, b.y, h2, l2);
            split_pk(b.z, b.w, h3, l3);
            XH[R][f] = (u32x4){h0, h1, h2, h3};
            XL[R][f] = (u32x4){l0, l1, l2, l3};
        }
    }

    // ---- x tiles at acc positions via symmetry (kept in regs; fits at 124 VGPR) ----
    float x00[16], x10[16], x01[16], x11[16];
#pragma unroll
    for (int g = 0; g < 4; ++g) {
        float4 t;
        t = *reinterpret_cast<const float4*>(rp0 + 4 * lh + 8 * g);
        x00[g*4+0] = t.x; x00[g*4+1] = t.y; x00[g*4+2] = t.z; x00[g*4+3] = t.w;
        t = *reinterpret_cast<const float4*>(rp0 + 32 + 4 * lh + 8 * g);
        x10[g*4+0] = t.x; x10[g*4+1] = t.y; x10[g*4+2] = t.z; x10[g*4+3] = t.w;
        t = *reinterpret_cast<const float4*>(rp1 + 4 * lh + 8 * g);
        x01[g*4+0] = t.x; x01[g*4+1] = t.y; x01[g*4+2] = t.z; x01[g*4+3] = t.w;
        t = *reinterpret_cast<const float4*>(rp1 + 32 + 4 * lh + 8 * g);
        x11[g*4+0] = t.x; x11[g*4+1] = t.y; x11[g*4+2] = t.z; x11[g*4+3] = t.w;
    }

    // ---- mm1: acc tiles of A*A ----
    f32x16 a00 = mm3v(XH[0], XL[0], XH[0], XL[0]);
    f32x16 a01 = mm3v(XH[0], XL[0], XH[1], XL[1]);
    f32x16 a10 = mm3v(XH[1], XL[1], XH[0], XL[0]);
    f32x16 a11 = mm3v(XH[1], XL[1], XH[1], XL[1]);

    float fr = 0.f;
#pragma unroll
    for (int r = 0; r < 16; ++r)
        fr += a00[r]*a00[r] + a01[r]*a01[r] + a10[r]*a10[r] + a11[r]*a11[r];
#pragma unroll
    for (int off = 32; off; off >>= 1) fr += __shfl_xor(fr, off);

    // ||A||_2 <= (sum (A^2)_ij^2)^(1/4); tolerate ||X|| <= 4
    const float bound = sqrtf(sqrtf(fr));
    int sexp = 0;
    if (bound > 4.f) {
        sexp = (int)ceilf(log2f(bound)) - 2;
        if (sexp < 0) sexp = 0;
        if (sexp > 24) sexp = 24;
    }
    const float sc1 = exp2f(-(float)sexp);
    const float sc2 = sc1 * sc1;

#pragma unroll
    for (int r = 0; r < 16; ++r) { x00[r] *= sc1; x10[r] *= sc1; x01[r] *= sc1; x11[r] *= sc1; }

    // ---- Yop = operand form of (A*A)*4^-s ----
    u32x4 YH[2][4], YL[2][4];
    {
        float v[16];
#pragma unroll
        for (int r = 0; r < 16; ++r) v[r] = a00[r] * sc2;
        tile_to_op(v, lh, &YH[0][0], &YL[0][0]);
#pragma unroll
        for (int r = 0; r < 16; ++r) v[r] = a10[r] * sc2;
        tile_to_op(v, lh, &YH[0][2], &YL[0][2]);
#pragma unroll
        for (int r = 0; r < 16; ++r) v[r] = a01[r] * sc2;
        tile_to_op(v, lh, &YH[1][0], &YL[1][0]);
#pragma unroll
        for (int r = 0; r < 16; ++r) v[r] = a11[r] * sc2;
        tile_to_op(v, lh, &YH[1][2], &YL[1][2]);
    }

    // ---- Pop init = operand form of CF[12]*I + CF[13]*X ----
    u32x4 PH[2][4], PL[2][4];
    {
        float v[16];
#pragma unroll
        for (int r = 0; r < 16; ++r)
            v[r] = CF[13] * x00[r] + (((dmask >> r) & 1) ? CF[12] : 0.f);
        tile_to_op(v, lh, &PH[0][0], &PL[0][0]);
#pragma unroll
        for (int r = 0; r < 16; ++r) v[r] = CF[13] * x10[r];
        tile_to_op(v, lh, &PH[0][2], &PL[0][2]);
#pragma unroll
        for (int r = 0; r < 16; ++r) v[r] = CF[13] * x01[r];
        tile_to_op(v, lh, &PH[1][0], &PL[1][0]);
#pragma unroll
        for (int r = 0; r < 16; ++r)
            v[r] = CF[13] * x11[r] + (((dmask >> r) & 1) ? CF[12] : 0.f);
        tile_to_op(v, lh, &PH[1][2], &PL[1][2]);
    }

    // ---- Horner (deg-13): P <- (cI*I + cX*X) + Y*P ----
    // Phased (2 accs live max) + MFMA C-in carries the polynomial terms.
#pragma unroll 1
    for (int j = 5; j >= 0; --j) {
        const float cI = CF[2 * j], cX = CF[2 * j + 1];
        const bool last = (j == 0) && (sexp == 0);
        {   // phase A: B-operand = P col-block 0
            f32x16 t0, t1;
#pragma unroll
            for (int r = 0; r < 16; ++r) {
                t0[r] = fmaf(cX, x00[r], (((dmask >> r) & 1) ? cI : 0.f));
                t1[r] = cX * x10[r];
            }
            t0 = mm3v_ci(YH[0], YL[0], PH[0], PL[0], t0);
            t1 = mm3v_ci(YH[1], YL[1], PH[0], PL[0], t1);
            if (last) {
                wr_tile(out, base, 0, 0, l31, lh, (const float*)&t0);
                wr_tile(out, base, 0, 1, l31, lh, (const float*)&t1);
            } else {
                tile_to_op((const float*)&t0, lh, &PH[0][0], &PL[0][0]);
                tile_to_op((const float*)&t1, lh, &PH[0][2], &PL[0][2]);
            }
        }
        {   // phase B: B-operand = OLD P col-block 1
            f32x16 t0, t1;
#pragma unroll
            for (int r = 0; r < 16; ++r) {
                t0[r] = cX * x01[r];
                t1[r] = fmaf(cX, x11[r], (((dmask >> r) & 1) ? cI : 0.f));
            }
            t0 = mm3v_ci(YH[0], YL[0], PH[1], PL[1], t0);
            t1 = mm3v_ci(YH[1], YL[1], PH[1], PL[1], t1);
            if (last) {
                wr_tile(out, base, 1, 0, l31, lh, (const float*)&t0);
                wr_tile(out, base, 1, 1, l31, lh, (const float*)&t1);
            } else {
                tile_to_op((const float*)&t0, lh, &PH[1][0], &PL[1][0]);
                tile_to_op((const float*)&t1, lh, &PH[1][2], &PL[1][2]);
            }
        }
    }

    // ---- squarings: P <- P*P ; final streams to global ----
#pragma unroll 1
    for (int t = 0; t < sexp; ++t) {
        f32x16 s00 = mm3v(PH[0], PL[0], PH[0], PL[0]);
        f32x16 s01 = mm3v(PH[0], PL[0], PH[1], PL[1]);
        f32x16 s10 = mm3v(PH[1], PL[1], PH[0], PL[0]);
        f32x16 s11 = mm3v(PH[1], PL[1], PH[1], PL[1]);
        if (t == sexp - 1) {
            wr_tile(out, base, 0, 0, l31, lh, (const float*)&s00);
            wr_tile(out, base, 0, 1, l31, lh, (const float*)&s10);
            wr_tile(out, base, 1, 0, l31, lh, (const float*)&s01);
            wr_tile(out, base, 1, 1, l31, lh, (const float*)&s11);
        } else {
            tile_to_op((const float*)&s00, lh, &PH[0][0], &PL[0][0]);
            tile_to_op((const float*)&s10, lh, &PH[0][2], &PL[0][2]);
            tile_to_op((const float*)&s01, lh, &PH[1][0], &PL[1][0]);
            tile_to_op((const float*)&s11, lh, &PH[1][2], &PL[1][2]);
        }
    }
}

extern "C" void kernel_launch(void* const* d_in, const int* in_sizes, int n_in,
                              void* d_out, int out_size, void* d_ws, size_t ws_size,
                              hipStream_t stream) {
    const float* in = reinterpret_cast<const float*>(d_in[0]);
    float* out = reinterpret_cast<float*>(d_out);
    const int nmat = in_sizes[0] / (NB * NB);
    hipLaunchKernelGGL(spd_expmap_reg, dim3(nmat), dim3(TPB), 0, stream, in, out);
}